// Round 5
// baseline (3871.344 us; speedup 1.0000x reference)
//
#include <hip/hip_runtime.h>
#include <hip/hip_bf16.h>

#define DMODEL 1024

// C[M=8192, N=1024] = A[M,1024] @ W[1024,1024] + bias, fp32 in/out.
// 64x64 tile, BK=16, 256 threads, 4x4 microtile.
__global__ __launch_bounds__(256) void gemm_bias(const float* __restrict__ A,
                                                 const float* __restrict__ W,
                                                 const float* __restrict__ bias,
                                                 float* __restrict__ C) {
  __shared__ float As[16][68];  // [kk][m]
  __shared__ float Bs[16][64];  // [kk][n]
  const int t = threadIdx.x;
  const int m0 = blockIdx.y * 64;
  const int n0 = blockIdx.x * 64;
  const int tr = t >> 4;
  const int tc = t & 15;
  const int am = t >> 2;
  const int ak = (t & 3) * 4;
  const int bk = t >> 4;
  const int bn = (t & 15) * 4;

  float acc[4][4];
#pragma unroll
  for (int i = 0; i < 4; ++i)
#pragma unroll
    for (int j = 0; j < 4; ++j) acc[i][j] = 0.f;

  for (int k0 = 0; k0 < DMODEL; k0 += 16) {
    __syncthreads();
    float4 av = *reinterpret_cast<const float4*>(&A[(size_t)(m0 + am) * DMODEL + k0 + ak]);
    As[ak + 0][am] = av.x;
    As[ak + 1][am] = av.y;
    As[ak + 2][am] = av.z;
    As[ak + 3][am] = av.w;
    *reinterpret_cast<float4*>(&Bs[bk][bn]) =
        *reinterpret_cast<const float4*>(&W[(size_t)(k0 + bk) * DMODEL + n0 + bn]);
    __syncthreads();
#pragma unroll
    for (int kk = 0; kk < 16; ++kk) {
      float4 a4 = *reinterpret_cast<const float4*>(&As[kk][tr * 4]);
      float4 b4 = *reinterpret_cast<const float4*>(&Bs[kk][tc * 4]);
      float a[4] = {a4.x, a4.y, a4.z, a4.w};
      float b[4] = {b4.x, b4.y, b4.z, b4.w};
#pragma unroll
      for (int i = 0; i < 4; ++i)
#pragma unroll
        for (int j = 0; j < 4; ++j) acc[i][j] = fmaf(a[i], b[j], acc[i][j]);
    }
  }
  float4 bb = *reinterpret_cast<const float4*>(&bias[n0 + tc * 4]);
  float bbv[4] = {bb.x, bb.y, bb.z, bb.w};
#pragma unroll
  for (int i = 0; i < 4; ++i) {
    const size_t row = (size_t)(m0 + tr * 4 + i);
#pragma unroll
    for (int j = 0; j < 4; ++j) {
      C[row * DMODEL + n0 + tc * 4 + j] = acc[i][j] + bbv[j];
    }
  }
}

// Fused mean-threshold-masked attention over one contiguous [1024,64] panel.
// Cross-validated against a brute-force per-row implementation (rounds 3/4
// produced bit-identical outputs). Two passes over K: A) row sum -> mean,
// row max; B) recompute s, p=(s>mean)?exp(s-mx):0, fused P@V + denom.
// O may alias Q: each block reads only its own 16 Q rows (into registers via
// Qs) and writes exactly those rows at the end; K/V are separate buffers.
__global__ __launch_bounds__(256) void attn_fused(const float* Q,
                                                  const float* __restrict__ K,
                                                  const float* __restrict__ V,
                                                  float* O) {
  __shared__ float Qs[16][68];
  __shared__ float Ks[64][68];
  __shared__ float Vs[64][68];
  const int t = threadIdx.x;
  const int g = blockIdx.x >> 6;               // panel = h*8+b, 0..127
  const int qr0 = (blockIdx.x & 63) << 4;      // first q-row of this block
  const float* Qg = Q + (size_t)g * 65536;
  const float* Kg = K + (size_t)g * 65536;
  const float* Vg = V + (size_t)g * 65536;

  {  // stage 16 Q rows (1024 floats = 256 float4, coalesced)
    float4 qv = *reinterpret_cast<const float4*>(&Qg[(size_t)qr0 * 64 + t * 4]);
    *reinterpret_cast<float4*>(&Qs[t >> 4][(t & 15) * 4]) = qv;
  }
  __syncthreads();
  const int r = t >> 4;   // q-row within block (16 lanes share a row)
  const int c = t & 15;   // owns k columns with k % 16 == c
  float4 q4[16];
#pragma unroll
  for (int i = 0; i < 16; ++i) q4[i] = *reinterpret_cast<const float4*>(&Qs[r][i * 4]);

  // ---- pass A: row sum + row max (masked max == row max: max > mean strictly)
  float sum = 0.f, mx = -INFINITY;
  for (int kc = 0; kc < 16; ++kc) {
    __syncthreads();
    const float* src = Kg + kc * 4096;
#pragma unroll
    for (int u = 0; u < 4; ++u) {
      const int f = t + u * 256;
      *reinterpret_cast<float4*>(&Ks[f >> 4][(f & 15) * 4]) =
          *reinterpret_cast<const float4*>(&src[(size_t)f * 4]);
    }
    __syncthreads();
#pragma unroll
    for (int j = 0; j < 4; ++j) {
      const int k = j * 16 + c;
      float s = 0.f;
#pragma unroll
      for (int dq = 0; dq < 16; ++dq) {
        float4 k4 = *reinterpret_cast<const float4*>(&Ks[k][dq * 4]);
        s = fmaf(q4[dq].x, k4.x, s);
        s = fmaf(q4[dq].y, k4.y, s);
        s = fmaf(q4[dq].z, k4.z, s);
        s = fmaf(q4[dq].w, k4.w, s);
      }
      s *= 0.03125f;  // 1/sqrt(1024)
      sum += s;
      mx = fmaxf(mx, s);
    }
  }
#pragma unroll
  for (int m = 1; m < 16; m <<= 1) {
    sum += __shfl_xor(sum, m, 64);
    mx = fmaxf(mx, __shfl_xor(mx, m, 64));
  }
  const float mean = sum * (1.0f / 1024.0f);

  // ---- pass B: masked softmax numerator fused with P@V
  float acc[64];
#pragma unroll
  for (int i = 0; i < 64; ++i) acc[i] = 0.f;
  float esum = 0.f;

  for (int kc = 0; kc < 16; ++kc) {
    __syncthreads();
    const float* ksrc = Kg + kc * 4096;
    const float* vsrc = Vg + kc * 4096;
#pragma unroll
    for (int u = 0; u < 4; ++u) {
      const int f = t + u * 256;
      *reinterpret_cast<float4*>(&Ks[f >> 4][(f & 15) * 4]) =
          *reinterpret_cast<const float4*>(&ksrc[(size_t)f * 4]);
      *reinterpret_cast<float4*>(&Vs[f >> 4][(f & 15) * 4]) =
          *reinterpret_cast<const float4*>(&vsrc[(size_t)f * 4]);
    }
    __syncthreads();
#pragma unroll
    for (int j = 0; j < 4; ++j) {
      const int k = j * 16 + c;
      float s = 0.f;
#pragma unroll
      for (int dq = 0; dq < 16; ++dq) {
        float4 k4 = *reinterpret_cast<const float4*>(&Ks[k][dq * 4]);
        s = fmaf(q4[dq].x, k4.x, s);
        s = fmaf(q4[dq].y, k4.y, s);
        s = fmaf(q4[dq].z, k4.z, s);
        s = fmaf(q4[dq].w, k4.w, s);
      }
      s *= 0.03125f;
      const float p = (s > mean) ? __expf(s - mx) : 0.f;
      esum += p;
#pragma unroll
      for (int dq = 0; dq < 16; ++dq) {
        float4 v4 = *reinterpret_cast<const float4*>(&Vs[k][dq * 4]);
        acc[dq * 4 + 0] = fmaf(p, v4.x, acc[dq * 4 + 0]);
        acc[dq * 4 + 1] = fmaf(p, v4.y, acc[dq * 4 + 1]);
        acc[dq * 4 + 2] = fmaf(p, v4.z, acc[dq * 4 + 2]);
        acc[dq * 4 + 3] = fmaf(p, v4.w, acc[dq * 4 + 3]);
      }
    }
  }
#pragma unroll
  for (int m = 1; m < 16; m <<= 1) esum += __shfl_xor(esum, m, 64);

  // halving exchange over the 16-lane row group; lane c ends with d=4c..4c+3
#pragma unroll
  for (int step = 0; step < 4; ++step) {
    const int m = 8 >> step;
    const int h = 32 >> step;
    const bool up = (c & m) != 0;
#pragma unroll
    for (int i = 0; i < h; ++i) {
      float sent = up ? acc[i] : acc[h + i];
      float recv = __shfl_xor(sent, m, 64);
      acc[i] = (up ? acc[h + i] : acc[i]) + recv;
    }
  }
  const float inv = 1.0f / esum;  // esum >= 1 (max entry survives, p=1)
  float4 o4;
  o4.x = acc[0] * inv;
  o4.y = acc[1] * inv;
  o4.z = acc[2] * inv;
  o4.w = acc[3] * inv;
  *reinterpret_cast<float4*>(&O[(size_t)g * 65536 + (size_t)(qr0 + r) * 64 + c * 4]) = o4;
}

extern "C" void kernel_launch(void* const* d_in, const int* in_sizes, int n_in,
                              void* d_out, int out_size, void* d_ws, size_t ws_size,
                              hipStream_t stream) {
  const float* x  = (const float*)d_in[0];
  const float* y  = (const float*)d_in[1];
  const float* Wq = (const float*)d_in[2];
  const float* bq = (const float*)d_in[3];
  const float* Wk = (const float*)d_in[4];
  const float* bk = (const float*)d_in[5];
  const float* Wv = (const float*)d_in[6];
  const float* bv = (const float*)d_in[7];
  const float* Wo = (const float*)d_in[8];
  const float* bo = (const float*)d_in[9];
  float* out = (float*)d_out;  // reference output dtype is float32

  float* ws = (float*)d_ws;
  const size_t NEL = 8192ull * 1024ull;
  float* Qp = ws;             // attention output aliases Qp (safe, see kernel)
  float* Kp = ws + NEL;
  float* Vp = ws + 2 * NEL;   // total ws use: 100.7 MB

  dim3 gblk(16, 128);  // (N/64, M/64)
  gemm_bias<<<gblk, 256, 0, stream>>>(x, Wq, bq, Qp);
  gemm_bias<<<gblk, 256, 0, stream>>>(y, Wk, bk, Kp);
  gemm_bias<<<gblk, 256, 0, stream>>>(y, Wv, bv, Vp);
  attn_fused<<<8192, 256, 0, stream>>>(Qp, Kp, Vp, Qp);
  gemm_bias<<<gblk, 256, 0, stream>>>(Qp, Wo, bo, out);
}

// Round 11
// 908.280 us; speedup vs baseline: 4.2623x; 4.2623x over previous
//
#include <hip/hip_runtime.h>
#include <hip/hip_bf16.h>

#define DMODEL 1024

using bf16x8 = __attribute__((ext_vector_type(8))) short;
using f32x4  = __attribute__((ext_vector_type(4))) float;

__device__ __forceinline__ ushort f2bf(float f) {  // RTNE fp32->bf16 bits
  unsigned u = __float_as_uint(f);
  u += 0x7FFFu + ((u >> 16) & 1u);
  return (ushort)(u >> 16);
}
__device__ __forceinline__ float bf2f(ushort h) {
  return __uint_as_float(((unsigned)h) << 16);
}

// One-shot weight prep: W[k][n] fp32 -> transposed hi/lo bf16 W^T[n][k].
// Reads coalesced; scatter writes are L2-absorbed (4.2 MB/weight, runs once).
__global__ __launch_bounds__(256) void wsplit(const float* __restrict__ W,
                                              ushort* __restrict__ Th,
                                              ushort* __restrict__ Tl) {
  const int idx = blockIdx.x * 256 + threadIdx.x;  // 0..2^20-1
  const int k = idx >> 10, n = idx & 1023;
  const float v = W[idx];
  const ushort h = f2bf(v);
  const ushort l = f2bf(v - bf2f(h));
  Th[n * 1024 + k] = h;
  Tl[n * 1024 + k] = l;
}

// C[M][1024] = A[M][1024](fp32) @ W + bias via split-precision bf16 MFMA.
// W given pre-split/pre-transposed as Bh_g/Bl_g = bf16(W^T[n][k]) hi/lo.
// BM=BN=128, BK=32; 256 thr = 4 waves, wave quadrant 64x64 (4x4 frags of
// 16x16x32). acc += ah*bh + ah*bl + al*bh (al*bl ~2^-18, dropped), fp32 acc.
// A is converted fp32->hi/lo bf16 during LDS staging.
// Frag layouts (HW-verified m89/m91): A/B operand: lane holds row(l&15)'s
// k-elems (l>>4)*8..+8; D: col=lane&15, row=(lane>>4)*4+reg.
__global__ __launch_bounds__(256) void gemm_mfma(const float* __restrict__ A,
                                                 const ushort* __restrict__ Bh_g,
                                                 const ushort* __restrict__ Bl_g,
                                                 const float* __restrict__ bias,
                                                 float* __restrict__ C) {
  __shared__ ushort Ah[128 * 40];  // row stride 40 bf16 = 80B (16B-aligned rows)
  __shared__ ushort Al[128 * 40];
  __shared__ ushort Bh[128 * 40];
  __shared__ ushort Bl[128 * 40];
  const int t = threadIdx.x;
  const int m0 = blockIdx.y * 128;
  const int n0 = blockIdx.x * 128;
  const int lane = t & 63;
  const int w = t >> 6;
  const int wr = w >> 1, wc = w & 1;   // 64x64 quadrant of the 128x128 tile
  const int l15 = lane & 15, l4 = lane >> 4;
  const int sr = t >> 1;               // staging row 0..127
  const int sc = (t & 1) * 16;         // staging col offset 0|16

  f32x4 acc[4][4];
#pragma unroll
  for (int i = 0; i < 4; ++i)
#pragma unroll
    for (int j = 0; j < 4; ++j) acc[i][j] = (f32x4){0.f, 0.f, 0.f, 0.f};

  for (int k0 = 0; k0 < DMODEL; k0 += 32) {
    __syncthreads();  // prev iter's frag reads done before overwrite
    {
      // ---- stage A: 16 fp32 -> hi/lo bf16
      const float* ap = &A[(size_t)(m0 + sr) * DMODEL + k0 + sc];
      float va[16];
#pragma unroll
      for (int u = 0; u < 4; ++u) {
        float4 f4 = *reinterpret_cast<const float4*>(ap + 4 * u);
        va[4 * u + 0] = f4.x; va[4 * u + 1] = f4.y;
        va[4 * u + 2] = f4.z; va[4 * u + 3] = f4.w;
      }
      ushort hh[16], ll[16];
#pragma unroll
      for (int u = 0; u < 16; ++u) {
        hh[u] = f2bf(va[u]);
        ll[u] = f2bf(va[u] - bf2f(hh[u]));
      }
#pragma unroll
      for (int half = 0; half < 2; ++half) {
        const ushort* hp = hh + 8 * half;
        const ushort* lp = ll + 8 * half;
        uint4 wh, wl;
        wh.x = hp[0] | ((unsigned)hp[1] << 16);
        wh.y = hp[2] | ((unsigned)hp[3] << 16);
        wh.z = hp[4] | ((unsigned)hp[5] << 16);
        wh.w = hp[6] | ((unsigned)hp[7] << 16);
        wl.x = lp[0] | ((unsigned)lp[1] << 16);
        wl.y = lp[2] | ((unsigned)lp[3] << 16);
        wl.z = lp[4] | ((unsigned)lp[5] << 16);
        wl.w = lp[6] | ((unsigned)lp[7] << 16);
        *reinterpret_cast<uint4*>(&Ah[sr * 40 + sc + 8 * half]) = wh;
        *reinterpret_cast<uint4*>(&Al[sr * 40 + sc + 8 * half]) = wl;
      }
      // ---- stage B: straight bf16 copy (pre-split, pre-transposed)
      const ushort* bhp = &Bh_g[(size_t)(n0 + sr) * DMODEL + k0 + sc];
      const ushort* blp = &Bl_g[(size_t)(n0 + sr) * DMODEL + k0 + sc];
#pragma unroll
      for (int half = 0; half < 2; ++half) {
        *reinterpret_cast<uint4*>(&Bh[sr * 40 + sc + 8 * half]) =
            *reinterpret_cast<const uint4*>(bhp + 8 * half);
        *reinterpret_cast<uint4*>(&Bl[sr * 40 + sc + 8 * half]) =
            *reinterpret_cast<const uint4*>(blp + 8 * half);
      }
    }
    __syncthreads();

    bf16x8 ah[4], al[4], bh[4], bl[4];
#pragma unroll
    for (int mb = 0; mb < 4; ++mb) {
      const int off = (wr * 64 + mb * 16 + l15) * 40 + l4 * 8;
      ah[mb] = *reinterpret_cast<const bf16x8*>(&Ah[off]);
      al[mb] = *reinterpret_cast<const bf16x8*>(&Al[off]);
    }
#pragma unroll
    for (int nb = 0; nb < 4; ++nb) {
      const int off = (wc * 64 + nb * 16 + l15) * 40 + l4 * 8;
      bh[nb] = *reinterpret_cast<const bf16x8*>(&Bh[off]);
      bl[nb] = *reinterpret_cast<const bf16x8*>(&Bl[off]);
    }
#pragma unroll
    for (int mb = 0; mb < 4; ++mb)
#pragma unroll
      for (int nb = 0; nb < 4; ++nb) {
        acc[mb][nb] = __builtin_amdgcn_mfma_f32_16x16x32_bf16(
            ah[mb], bh[nb], acc[mb][nb], 0, 0, 0);
        acc[mb][nb] = __builtin_amdgcn_mfma_f32_16x16x32_bf16(
            ah[mb], bl[nb], acc[mb][nb], 0, 0, 0);
        acc[mb][nb] = __builtin_amdgcn_mfma_f32_16x16x32_bf16(
            al[mb], bh[nb], acc[mb][nb], 0, 0, 0);
      }
  }

  // epilogue: D frag (mb,nb) reg r -> C[row0+r][col], + bias[col]
#pragma unroll
  for (int nb = 0; nb < 4; ++nb) {
    const int col = n0 + wc * 64 + nb * 16 + l15;
    const float bv = bias[col];
#pragma unroll
    for (int mb = 0; mb < 4; ++mb) {
      const int row0 = m0 + wr * 64 + mb * 16 + l4 * 4;
#pragma unroll
      for (int r = 0; r < 4; ++r)
        C[(size_t)(row0 + r) * DMODEL + col] = acc[mb][nb][r] + bv;
    }
  }
}

// Per-panel column sum of K: Ksum[g][d] = sum_k K[g][k][d]. (frozen, round 5)
__global__ __launch_bounds__(256) void ksum_kernel(const float* __restrict__ K,
                                                   float* __restrict__ Ksum) {
  __shared__ float red[4][64];
  const int t = threadIdx.x;
  const int g = blockIdx.x;
  const int d = t & 63;
  const int sub = t >> 6;
  const float* base = K + (size_t)g * 65536 + (size_t)(sub * 256) * 64 + d;
  float s = 0.f;
#pragma unroll 8
  for (int k = 0; k < 256; ++k) s += base[(size_t)k * 64];
  red[sub][d] = s;
  __syncthreads();
  if (t < 64) Ksum[g * 64 + t] = red[0][t] + red[1][t] + red[2][t] + red[3][t];
}

// Single-pass mean-threshold-masked attention. (frozen, round 5 — see notes)
__global__ __launch_bounds__(256) void attn2(const float* Q,
                                             const float* __restrict__ K,
                                             const float* __restrict__ V,
                                             const float* __restrict__ Ksum,
                                             float* O) {
  __shared__ float Qt[64][68];   // [d][q] transposed Q tile
  __shared__ float Kt[64][68];   // [d][k] transposed K tile
  __shared__ float Vs[64][68];   // [k][d] natural V tile
  __shared__ float Ps[64][68];   // [q][k] masked-exp tile
  __shared__ float meanv[64];
  const int t = threadIdx.x;
  const int g = blockIdx.x & 127;
  const int qt = blockIdx.x >> 7;
  const int qr0 = qt * 64;
  const float* Qg = Q + (size_t)g * 65536 + (size_t)qr0 * 64;
  const float* Kg = K + (size_t)g * 65536;
  const float* Vg = V + (size_t)g * 65536;

  {
    const int kk = t >> 2, f0 = t & 3;
#pragma unroll
    for (int u = 0; u < 4; ++u) {
      const int d0 = 4 * (f0 + 4 * u);
      float4 v4 = *reinterpret_cast<const float4*>(&Qg[kk * 64 + d0]);
      Qt[d0 + 0][kk] = v4.x;
      Qt[d0 + 1][kk] = v4.y;
      Qt[d0 + 2][kk] = v4.z;
      Qt[d0 + 3][kk] = v4.w;
    }
  }
  __syncthreads();
  if (t < 64) {
    const float* ks = Ksum + g * 64;
    float dot = 0.f;
#pragma unroll 8
    for (int d = 0; d < 64; ++d) dot = fmaf(Qt[d][t], ks[d], dot);
    meanv[t] = dot * (0.03125f / 1024.0f);
  }
  __syncthreads();

  const int rq = t >> 4;
  const int c = t & 15;
  float m4[4];
#pragma unroll
  for (int i = 0; i < 4; ++i) m4[i] = meanv[4 * rq + i];

  float acc[4][4];
#pragma unroll
  for (int i = 0; i < 4; ++i)
#pragma unroll
    for (int j = 0; j < 4; ++j) acc[i][j] = 0.f;
  float den[4] = {0.f, 0.f, 0.f, 0.f};

  for (int kc = 0; kc < 16; ++kc) {
    __syncthreads();
    {
      const int kk = t >> 2, f0 = t & 3;
      const float* krow = Kg + (size_t)(kc * 64 + kk) * 64;
      const float* vrow = Vg + (size_t)(kc * 64 + kk) * 64;
#pragma unroll
      for (int u = 0; u < 4; ++u) {
        const int d0 = 4 * (f0 + 4 * u);
        float4 kv = *reinterpret_cast<const float4*>(&krow[d0]);
        Kt[d0 + 0][kk] = kv.x;
        Kt[d0 + 1][kk] = kv.y;
        Kt[d0 + 2][kk] = kv.z;
        Kt[d0 + 3][kk] = kv.w;
        *reinterpret_cast<float4*>(&Vs[kk][d0]) =
            *reinterpret_cast<const float4*>(&vrow[d0]);
      }
    }
    __syncthreads();

    float s[4][4];
#pragma unroll
    for (int i = 0; i < 4; ++i)
#pragma unroll
      for (int j = 0; j < 4; ++j) s[i][j] = 0.f;
#pragma unroll 16
    for (int d = 0; d < 64; ++d) {
      float4 a4 = *reinterpret_cast<const float4*>(&Qt[d][4 * rq]);
      float4 b4 = *reinterpret_cast<const float4*>(&Kt[d][4 * c]);
      float a[4] = {a4.x, a4.y, a4.z, a4.w};
      float b[4] = {b4.x, b4.y, b4.z, b4.w};
#pragma unroll
      for (int i = 0; i < 4; ++i)
#pragma unroll
        for (int j = 0; j < 4; ++j) s[i][j] = fmaf(a[i], b[j], s[i][j]);
    }
#pragma unroll
    for (int i = 0; i < 4; ++i) {
      float p0 = (s[i][0] * 0.03125f > m4[i]) ? __expf(s[i][0] * 0.03125f) : 0.f;
      float p1 = (s[i][1] * 0.03125f > m4[i]) ? __expf(s[i][1] * 0.03125f) : 0.f;
      float p2 = (s[i][2] * 0.03125f > m4[i]) ? __expf(s[i][2] * 0.03125f) : 0.f;
      float p3 = (s[i][3] * 0.03125f > m4[i]) ? __expf(s[i][3] * 0.03125f) : 0.f;
      den[i] += (p0 + p1) + (p2 + p3);
      float4 pv = make_float4(p0, p1, p2, p3);
      *reinterpret_cast<float4*>(&Ps[4 * rq + i][4 * c]) = pv;
    }
    __syncthreads();

#pragma unroll 16
    for (int k = 0; k < 64; ++k) {
      float4 v4 = *reinterpret_cast<const float4*>(&Vs[k][4 * c]);
      float p0 = Ps[4 * rq + 0][k];
      float p1 = Ps[4 * rq + 1][k];
      float p2 = Ps[4 * rq + 2][k];
      float p3 = Ps[4 * rq + 3][k];
      acc[0][0] = fmaf(p0, v4.x, acc[0][0]);
      acc[0][1] = fmaf(p0, v4.y, acc[0][1]);
      acc[0][2] = fmaf(p0, v4.z, acc[0][2]);
      acc[0][3] = fmaf(p0, v4.w, acc[0][3]);
      acc[1][0] = fmaf(p1, v4.x, acc[1][0]);
      acc[1][1] = fmaf(p1, v4.y, acc[1][1]);
      acc[1][2] = fmaf(p1, v4.z, acc[1][2]);
      acc[1][3] = fmaf(p1, v4.w, acc[1][3]);
      acc[2][0] = fmaf(p2, v4.x, acc[2][0]);
      acc[2][1] = fmaf(p2, v4.y, acc[2][1]);
      acc[2][2] = fmaf(p2, v4.z, acc[2][2]);
      acc[2][3] = fmaf(p2, v4.w, acc[2][3]);
      acc[3][0] = fmaf(p3, v4.x, acc[3][0]);
      acc[3][1] = fmaf(p3, v4.y, acc[3][1]);
      acc[3][2] = fmaf(p3, v4.z, acc[3][2]);
      acc[3][3] = fmaf(p3, v4.w, acc[3][3]);
    }
  }

#pragma unroll
  for (int m = 1; m < 16; m <<= 1)
#pragma unroll
    for (int i = 0; i < 4; ++i) den[i] += __shfl_xor(den[i], m, 64);

  float* Og = O + (size_t)g * 65536 + (size_t)qr0 * 64;
#pragma unroll
  for (int i = 0; i < 4; ++i) {
    const float inv = 1.0f / den[i];
    float4 o4 = make_float4(acc[i][0] * inv, acc[i][1] * inv, acc[i][2] * inv,
                            acc[i][3] * inv);
    *reinterpret_cast<float4*>(&Og[(4 * rq + i) * 64 + 4 * c]) = o4;
  }
}

extern "C" void kernel_launch(void* const* d_in, const int* in_sizes, int n_in,
                              void* d_out, int out_size, void* d_ws, size_t ws_size,
                              hipStream_t stream) {
  const float* x  = (const float*)d_in[0];
  const float* y  = (const float*)d_in[1];
  const float* Wq = (const float*)d_in[2];
  const float* bq = (const float*)d_in[3];
  const float* Wk = (const float*)d_in[4];
  const float* bk = (const float*)d_in[5];
  const float* Wv = (const float*)d_in[6];
  const float* bv = (const float*)d_in[7];
  const float* Wo = (const float*)d_in[8];
  const float* bo = (const float*)d_in[9];
  float* out = (float*)d_out;  // reference output dtype is float32

  float* ws = (float*)d_ws;
  const size_t NEL = 8192ull * 1024ull;
  const size_t WN = 1024ull * 1024ull;
  float* Qp = ws;              // attention output aliases Qp (safe, see attn2)
  float* Kp = ws + NEL;
  float* Vp = ws + 2 * NEL;
  float* Ks = ws + 3 * NEL;    // 8192 floats
  ushort* wt = (ushort*)(ws + 3 * NEL + 8192);
  ushort* WqTh = wt + 0 * WN;  // 8 x 2MB of pre-split transposed weights
  ushort* WqTl = wt + 1 * WN;
  ushort* WkTh = wt + 2 * WN;
  ushort* WkTl = wt + 3 * WN;
  ushort* WvTh = wt + 4 * WN;
  ushort* WvTl = wt + 5 * WN;
  ushort* WoTh = wt + 6 * WN;
  ushort* WoTl = wt + 7 * WN;  // total ws use ~117.5 MB (proven-safe < 134)

  wsplit<<<4096, 256, 0, stream>>>(Wq, WqTh, WqTl);
  wsplit<<<4096, 256, 0, stream>>>(Wk, WkTh, WkTl);
  wsplit<<<4096, 256, 0, stream>>>(Wv, WvTh, WvTl);
  wsplit<<<4096, 256, 0, stream>>>(Wo, WoTh, WoTl);

  dim3 gmm(8, 64);  // (N/128, M/128)
  gemm_mfma<<<gmm, 256, 0, stream>>>(x, WqTh, WqTl, bq, Qp);
  gemm_mfma<<<gmm, 256, 0, stream>>>(y, WkTh, WkTl, bk, Kp);
  gemm_mfma<<<gmm, 256, 0, stream>>>(y, WvTh, WvTl, bv, Vp);
  ksum_kernel<<<128, 256, 0, stream>>>(Kp, Ks);
  attn2<<<2048, 256, 0, stream>>>(Qp, Kp, Vp, Ks, Qp);
  gemm_mfma<<<gmm, 256, 0, stream>>>(Qp, WoTh, WoTl, bo, out);
}

// Round 12
// 562.714 us; speedup vs baseline: 6.8798x; 1.6141x over previous
//
#include <hip/hip_runtime.h>
#include <hip/hip_bf16.h>

#define DMODEL 1024

using bf16x8 = __attribute__((ext_vector_type(8))) short;
using f32x4  = __attribute__((ext_vector_type(4))) float;

__device__ __forceinline__ ushort f2bf(float f) {  // RTNE fp32->bf16 bits
  unsigned u = __float_as_uint(f);
  u += 0x7FFFu + ((u >> 16) & 1u);
  return (ushort)(u >> 16);
}
__device__ __forceinline__ float bf2f(ushort h) {
  return __uint_as_float(((unsigned)h) << 16);
}

// One-shot weight prep: W[k][n] fp32 -> transposed hi/lo bf16 W^T[n][k].
__global__ __launch_bounds__(256) void wsplit(const float* __restrict__ W,
                                              ushort* __restrict__ Th,
                                              ushort* __restrict__ Tl) {
  const int idx = blockIdx.x * 256 + threadIdx.x;  // 0..2^20-1
  const int k = idx >> 10, n = idx & 1023;
  const float v = W[idx];
  const ushort h = f2bf(v);
  const ushort l = f2bf(v - bf2f(h));
  Th[n * 1024 + k] = h;
  Tl[n * 1024 + k] = l;
}

// C[M][1024] = A(fp32) @ W + bias via split-precision bf16 MFMA. (verified r11)
__global__ __launch_bounds__(256) void gemm_mfma(const float* __restrict__ A,
                                                 const ushort* __restrict__ Bh_g,
                                                 const ushort* __restrict__ Bl_g,
                                                 const float* __restrict__ bias,
                                                 float* __restrict__ C) {
  __shared__ ushort Ah[128 * 40];
  __shared__ ushort Al[128 * 40];
  __shared__ ushort Bh[128 * 40];
  __shared__ ushort Bl[128 * 40];
  const int t = threadIdx.x;
  const int m0 = blockIdx.y * 128;
  const int n0 = blockIdx.x * 128;
  const int lane = t & 63;
  const int w = t >> 6;
  const int wr = w >> 1, wc = w & 1;
  const int l15 = lane & 15, l4 = lane >> 4;
  const int sr = t >> 1;
  const int sc = (t & 1) * 16;

  f32x4 acc[4][4];
#pragma unroll
  for (int i = 0; i < 4; ++i)
#pragma unroll
    for (int j = 0; j < 4; ++j) acc[i][j] = (f32x4){0.f, 0.f, 0.f, 0.f};

  for (int k0 = 0; k0 < DMODEL; k0 += 32) {
    __syncthreads();
    {
      const float* ap = &A[(size_t)(m0 + sr) * DMODEL + k0 + sc];
      float va[16];
#pragma unroll
      for (int u = 0; u < 4; ++u) {
        float4 f4 = *reinterpret_cast<const float4*>(ap + 4 * u);
        va[4 * u + 0] = f4.x; va[4 * u + 1] = f4.y;
        va[4 * u + 2] = f4.z; va[4 * u + 3] = f4.w;
      }
      ushort hh[16], ll[16];
#pragma unroll
      for (int u = 0; u < 16; ++u) {
        hh[u] = f2bf(va[u]);
        ll[u] = f2bf(va[u] - bf2f(hh[u]));
      }
#pragma unroll
      for (int half = 0; half < 2; ++half) {
        const ushort* hp = hh + 8 * half;
        const ushort* lp = ll + 8 * half;
        uint4 wh, wl;
        wh.x = hp[0] | ((unsigned)hp[1] << 16);
        wh.y = hp[2] | ((unsigned)hp[3] << 16);
        wh.z = hp[4] | ((unsigned)hp[5] << 16);
        wh.w = hp[6] | ((unsigned)hp[7] << 16);
        wl.x = lp[0] | ((unsigned)lp[1] << 16);
        wl.y = lp[2] | ((unsigned)lp[3] << 16);
        wl.z = lp[4] | ((unsigned)lp[5] << 16);
        wl.w = lp[6] | ((unsigned)lp[7] << 16);
        *reinterpret_cast<uint4*>(&Ah[sr * 40 + sc + 8 * half]) = wh;
        *reinterpret_cast<uint4*>(&Al[sr * 40 + sc + 8 * half]) = wl;
      }
      const ushort* bhp = &Bh_g[(size_t)(n0 + sr) * DMODEL + k0 + sc];
      const ushort* blp = &Bl_g[(size_t)(n0 + sr) * DMODEL + k0 + sc];
#pragma unroll
      for (int half = 0; half < 2; ++half) {
        *reinterpret_cast<uint4*>(&Bh[sr * 40 + sc + 8 * half]) =
            *reinterpret_cast<const uint4*>(bhp + 8 * half);
        *reinterpret_cast<uint4*>(&Bl[sr * 40 + sc + 8 * half]) =
            *reinterpret_cast<const uint4*>(blp + 8 * half);
      }
    }
    __syncthreads();

    bf16x8 ah[4], al[4], bh[4], bl[4];
#pragma unroll
    for (int mb = 0; mb < 4; ++mb) {
      const int off = (wr * 64 + mb * 16 + l15) * 40 + l4 * 8;
      ah[mb] = *reinterpret_cast<const bf16x8*>(&Ah[off]);
      al[mb] = *reinterpret_cast<const bf16x8*>(&Al[off]);
    }
#pragma unroll
    for (int nb = 0; nb < 4; ++nb) {
      const int off = (wc * 64 + nb * 16 + l15) * 40 + l4 * 8;
      bh[nb] = *reinterpret_cast<const bf16x8*>(&Bh[off]);
      bl[nb] = *reinterpret_cast<const bf16x8*>(&Bl[off]);
    }
#pragma unroll
    for (int mb = 0; mb < 4; ++mb)
#pragma unroll
      for (int nb = 0; nb < 4; ++nb) {
        acc[mb][nb] = __builtin_amdgcn_mfma_f32_16x16x32_bf16(
            ah[mb], bh[nb], acc[mb][nb], 0, 0, 0);
        acc[mb][nb] = __builtin_amdgcn_mfma_f32_16x16x32_bf16(
            ah[mb], bl[nb], acc[mb][nb], 0, 0, 0);
        acc[mb][nb] = __builtin_amdgcn_mfma_f32_16x16x32_bf16(
            al[mb], bh[nb], acc[mb][nb], 0, 0, 0);
      }
  }

#pragma unroll
  for (int nb = 0; nb < 4; ++nb) {
    const int col = n0 + wc * 64 + nb * 16 + l15;
    const float bv = bias[col];
#pragma unroll
    for (int mb = 0; mb < 4; ++mb) {
      const int row0 = m0 + wr * 64 + mb * 16 + l4 * 4;
#pragma unroll
      for (int r = 0; r < 4; ++r)
        C[(size_t)(row0 + r) * DMODEL + col] = acc[mb][nb][r] + bv;
    }
  }
}

// Per-panel column sum of K. (frozen, round 5)
__global__ __launch_bounds__(256) void ksum_kernel(const float* __restrict__ K,
                                                   float* __restrict__ Ksum) {
  __shared__ float red[4][64];
  const int t = threadIdx.x;
  const int g = blockIdx.x;
  const int d = t & 63;
  const int sub = t >> 6;
  const float* base = K + (size_t)g * 65536 + (size_t)(sub * 256) * 64 + d;
  float s = 0.f;
#pragma unroll 8
  for (int k = 0; k < 256; ++k) s += base[(size_t)k * 64];
  red[sub][d] = s;
  __syncthreads();
  if (t < 64) Ksum[g * 64 + t] = red[0][t] + red[1][t] + red[2][t] + red[3][t];
}

// MFMA attention: QK^T split-precision bf16 (3 MFMA), PV plain bf16.
// Block = (panel g, 64 q-rows); 4 waves, each owns 16 q-rows.
// Mean via Ksum linearity; softmax shift 0 (scores bounded, exp<=~3).
// Per kc (64 k): stage K hi/lo [k][d] + V^T [d][k] bf16; S-frags -> mask/exp
// -> Ps LDS bf16 [q][k]; PV MFMA. den per q in regs, l15-reduced at end.
// O aliases Q: block reads only its own 64 Q rows (regs+mean at start),
// writes exactly those rows at the end.
__global__ __launch_bounds__(256) void attn3(const float* Q,
                                             const float* __restrict__ K,
                                             const float* __restrict__ V,
                                             const float* __restrict__ Ksum,
                                             float* O) {
  __shared__ __align__(16) ushort Kh[64 * 72];  // [k][d] hi
  __shared__ __align__(16) ushort Kl[64 * 72];  // [k][d] lo
  __shared__ __align__(16) ushort Vt[64 * 72];  // [d][k] bf16 (transposed V)
  __shared__ __align__(16) ushort Ps[64 * 72];  // [q][k] bf16 masked-exp
  __shared__ float meanv[64];
  __shared__ float red[4][64];
  const int t = threadIdx.x;
  const int g = blockIdx.x & 127;
  const int qt = blockIdx.x >> 7;
  const float* Qg = Q + (size_t)g * 65536 + (size_t)(qt * 64) * 64;
  const float* Kg = K + (size_t)g * 65536;
  const float* Vg = V + (size_t)g * 65536;

  {  // mean_q = (Q[q] . Ksum) * scale / 1024
    const int q = t & 63, sub = t >> 6;
    const float* qp = Qg + q * 64 + sub * 16;
    const float* ks = Ksum + g * 64 + sub * 16;
    float dot = 0.f;
#pragma unroll
    for (int u = 0; u < 4; ++u) {
      float4 a = *reinterpret_cast<const float4*>(qp + 4 * u);
      float4 b = *reinterpret_cast<const float4*>(ks + 4 * u);
      dot = fmaf(a.x, b.x, dot); dot = fmaf(a.y, b.y, dot);
      dot = fmaf(a.z, b.z, dot); dot = fmaf(a.w, b.w, dot);
    }
    red[sub][q] = dot;
  }
  __syncthreads();
  if (t < 64)
    meanv[t] = (red[0][t] + red[1][t] + red[2][t] + red[3][t]) * (0.03125f / 1024.0f);
  __syncthreads();

  const int lane = t & 63, w = t >> 6;
  const int l15 = lane & 15, l4 = lane >> 4;

  // Q fragments in registers for the whole kernel: row w*16+l15, d=ks2*32+l4*8
  bf16x8 qh[2], ql[2];
#pragma unroll
  for (int ks2 = 0; ks2 < 2; ++ks2) {
    const float* qp = Qg + (size_t)(w * 16 + l15) * 64 + ks2 * 32 + l4 * 8;
    float va[8];
#pragma unroll
    for (int u = 0; u < 2; ++u) {
      float4 f4 = *reinterpret_cast<const float4*>(qp + 4 * u);
      va[4 * u + 0] = f4.x; va[4 * u + 1] = f4.y;
      va[4 * u + 2] = f4.z; va[4 * u + 3] = f4.w;
    }
#pragma unroll
    for (int j = 0; j < 8; ++j) {
      const ushort h = f2bf(va[j]);
      qh[ks2][j] = (short)h;
      ql[ks2][j] = (short)f2bf(va[j] - bf2f(h));
    }
  }

  float m4[4];
#pragma unroll
  for (int r = 0; r < 4; ++r) m4[r] = meanv[w * 16 + l4 * 4 + r];

  f32x4 acc[4];
#pragma unroll
  for (int nb = 0; nb < 4; ++nb) acc[nb] = (f32x4){0.f, 0.f, 0.f, 0.f};
  float den[4] = {0.f, 0.f, 0.f, 0.f};

  for (int kc = 0; kc < 16; ++kc) {
    __syncthreads();  // prev PV reads done before overwriting tiles
    {
      const int kk = t >> 2, f0 = t & 3;  // row kk, 16 d's starting f0*16
      const float* krow = Kg + (size_t)(kc * 64 + kk) * 64 + f0 * 16;
      const float* vrow = Vg + (size_t)(kc * 64 + kk) * 64 + f0 * 16;
      float kv[16], vv[16];
#pragma unroll
      for (int u = 0; u < 4; ++u) {
        float4 a = *reinterpret_cast<const float4*>(krow + 4 * u);
        kv[4 * u + 0] = a.x; kv[4 * u + 1] = a.y;
        kv[4 * u + 2] = a.z; kv[4 * u + 3] = a.w;
        float4 b = *reinterpret_cast<const float4*>(vrow + 4 * u);
        vv[4 * u + 0] = b.x; vv[4 * u + 1] = b.y;
        vv[4 * u + 2] = b.z; vv[4 * u + 3] = b.w;
      }
      ushort kh16[16], kl16[16];
#pragma unroll
      for (int j = 0; j < 16; ++j) {
        kh16[j] = f2bf(kv[j]);
        kl16[j] = f2bf(kv[j] - bf2f(kh16[j]));
      }
#pragma unroll
      for (int half = 0; half < 2; ++half) {
        const ushort* hp = kh16 + 8 * half;
        const ushort* lp = kl16 + 8 * half;
        uint4 wh, wl;
        wh.x = hp[0] | ((unsigned)hp[1] << 16);
        wh.y = hp[2] | ((unsigned)hp[3] << 16);
        wh.z = hp[4] | ((unsigned)hp[5] << 16);
        wh.w = hp[6] | ((unsigned)hp[7] << 16);
        wl.x = lp[0] | ((unsigned)lp[1] << 16);
        wl.y = lp[2] | ((unsigned)lp[3] << 16);
        wl.z = lp[4] | ((unsigned)lp[5] << 16);
        wl.w = lp[6] | ((unsigned)lp[7] << 16);
        *reinterpret_cast<uint4*>(&Kh[kk * 72 + f0 * 16 + 8 * half]) = wh;
        *reinterpret_cast<uint4*>(&Kl[kk * 72 + f0 * 16 + 8 * half]) = wl;
      }
#pragma unroll
      for (int j = 0; j < 16; ++j)
        Vt[(f0 * 16 + j) * 72 + kk] = f2bf(vv[j]);  // transposed scatter
    }
    __syncthreads();

    // ---- S = Q.K^T (split precision), mask + exp, publish P
#pragma unroll
    for (int nb = 0; nb < 4; ++nb) {
      f32x4 s = (f32x4){0.f, 0.f, 0.f, 0.f};
#pragma unroll
      for (int ks2 = 0; ks2 < 2; ++ks2) {
        const int boff = (nb * 16 + l15) * 72 + ks2 * 32 + l4 * 8;
        bf16x8 kbh = *reinterpret_cast<const bf16x8*>(&Kh[boff]);
        bf16x8 kbl = *reinterpret_cast<const bf16x8*>(&Kl[boff]);
        s = __builtin_amdgcn_mfma_f32_16x16x32_bf16(qh[ks2], kbh, s, 0, 0, 0);
        s = __builtin_amdgcn_mfma_f32_16x16x32_bf16(qh[ks2], kbl, s, 0, 0, 0);
        s = __builtin_amdgcn_mfma_f32_16x16x32_bf16(ql[ks2], kbh, s, 0, 0, 0);
      }
#pragma unroll
      for (int r = 0; r < 4; ++r) {
        const float sv = s[r] * 0.03125f;
        const float p = (sv > m4[r]) ? __expf(sv) : 0.f;
        den[r] += p;
        Ps[(w * 16 + l4 * 4 + r) * 72 + nb * 16 + l15] = f2bf(p);
      }
    }
    __syncthreads();  // Ps visible to all lanes of the wave's A-frag reads

    // ---- O += P.V (plain bf16)
    bf16x8 pa[2];
#pragma unroll
    for (int ks2 = 0; ks2 < 2; ++ks2)
      pa[ks2] = *reinterpret_cast<const bf16x8*>(
          &Ps[(w * 16 + l15) * 72 + ks2 * 32 + l4 * 8]);
#pragma unroll
    for (int nb = 0; nb < 4; ++nb) {
#pragma unroll
      for (int ks2 = 0; ks2 < 2; ++ks2) {
        bf16x8 vb = *reinterpret_cast<const bf16x8*>(
            &Vt[(nb * 16 + l15) * 72 + ks2 * 32 + l4 * 8]);
        acc[nb] = __builtin_amdgcn_mfma_f32_16x16x32_bf16(pa[ks2], vb, acc[nb], 0, 0, 0);
      }
    }
  }

#pragma unroll
  for (int m = 1; m < 16; m <<= 1)
#pragma unroll
    for (int r = 0; r < 4; ++r) den[r] += __shfl_xor(den[r], m, 64);

  float* Og = O + (size_t)g * 65536 + (size_t)(qt * 64) * 64;
#pragma unroll
  for (int r = 0; r < 4; ++r) {
    const float inv = 1.0f / den[r];
    const int q = w * 16 + l4 * 4 + r;
#pragma unroll
    for (int nb = 0; nb < 4; ++nb)
      Og[(size_t)q * 64 + nb * 16 + l15] = acc[nb][r] * inv;
  }
}

extern "C" void kernel_launch(void* const* d_in, const int* in_sizes, int n_in,
                              void* d_out, int out_size, void* d_ws, size_t ws_size,
                              hipStream_t stream) {
  const float* x  = (const float*)d_in[0];
  const float* y  = (const float*)d_in[1];
  const float* Wq = (const float*)d_in[2];
  const float* bq = (const float*)d_in[3];
  const float* Wk = (const float*)d_in[4];
  const float* bk = (const float*)d_in[5];
  const float* Wv = (const float*)d_in[6];
  const float* bv = (const float*)d_in[7];
  const float* Wo = (const float*)d_in[8];
  const float* bo = (const float*)d_in[9];
  float* out = (float*)d_out;  // reference output dtype is float32

  float* ws = (float*)d_ws;
  const size_t NEL = 8192ull * 1024ull;
  const size_t WN = 1024ull * 1024ull;
  float* Qp = ws;              // attention output aliases Qp (safe, see attn3)
  float* Kp = ws + NEL;
  float* Vp = ws + 2 * NEL;
  float* Ks = ws + 3 * NEL;    // 8192 floats
  ushort* wt = (ushort*)(ws + 3 * NEL + 8192);
  ushort* WqTh = wt + 0 * WN;
  ushort* WqTl = wt + 1 * WN;
  ushort* WkTh = wt + 2 * WN;
  ushort* WkTl = wt + 3 * WN;
  ushort* WvTh = wt + 4 * WN;
  ushort* WvTl = wt + 5 * WN;
  ushort* WoTh = wt + 6 * WN;
  ushort* WoTl = wt + 7 * WN;  // total ws ~117.5 MB (proven-safe < 134)

  wsplit<<<4096, 256, 0, stream>>>(Wq, WqTh, WqTl);
  wsplit<<<4096, 256, 0, stream>>>(Wk, WkTh, WkTl);
  wsplit<<<4096, 256, 0, stream>>>(Wv, WvTh, WvTl);
  wsplit<<<4096, 256, 0, stream>>>(Wo, WoTh, WoTl);

  dim3 gmm(8, 64);  // (N/128, M/128)
  gemm_mfma<<<gmm, 256, 0, stream>>>(x, WqTh, WqTl, bq, Qp);
  gemm_mfma<<<gmm, 256, 0, stream>>>(y, WkTh, WkTl, bk, Kp);
  gemm_mfma<<<gmm, 256, 0, stream>>>(y, WvTh, WvTl, bv, Vp);
  ksum_kernel<<<128, 256, 0, stream>>>(Kp, Ks);
  attn3<<<2048, 256, 0, stream>>>(Qp, Kp, Vp, Ks, Qp);
  gemm_mfma<<<gmm, 256, 0, stream>>>(Qp, WoTh, WoTl, bo, out);
}